// Round 22
// baseline (325.302 us; speedup 1.0000x reference)
//
#include <hip/hip_runtime.h>
#include <hip/hip_bf16.h>

#ifndef D_FEAT
#define D_FEAT 128
#endif

#define SLOTS 48          // ELL width: 192B row = 3 aligned 64B lines
#define OVF_CAP 8192
#define BWN 256           // bucket width (nodes); NB = ceil(N/256)
#define CAPB 4608         // staging capacity/bucket (mean 4096 + 8 sigma)
#define CHUNK_A 4096      // edges per split block

typedef __attribute__((ext_vector_type(8))) short bf16x8;
typedef __attribute__((ext_vector_type(4))) float f32x4;
typedef __attribute__((ext_vector_type(2))) unsigned uint2v;
typedef __attribute__((ext_vector_type(4))) unsigned uint4v;
typedef unsigned long long u64;

// ---------------- bf16 helpers (RN-even) ----------------
__device__ __forceinline__ unsigned short f2bf(float f) {
    union { float f; unsigned u; } v; v.f = f;
    unsigned r = v.u + 0x7FFF + ((v.u >> 16) & 1);
    return (unsigned short)(r >> 16);
}
__device__ __forceinline__ float bf2f_lo(unsigned u) {
    union { unsigned u; float f; } v; v.u = u << 16; return v.f;
}
__device__ __forceinline__ float bf2f_hi(unsigned u) {
    union { unsigned u; float f; } v; v.u = u & 0xFFFF0000u; return v.f;
}

// ---------------------------------------------------------------------------
// W-pack body (canonical B-fragment order):
// Wp[((ks*8+ct)*64+lane)*8+j] = W[ks*32+(lane>>4)*8+j][ct*16+(lane&15)]
// ---------------------------------------------------------------------------
__device__ __forceinline__ void pack_W_body(const float* __restrict__ Wr,
                                            const float* __restrict__ Ws,
                                            unsigned short* __restrict__ Wp,
                                            int t) {
    const int lane = t & 63;
    const int ct = (t >> 6) & 7;
    const int ks = t >> 9;
    const int col = ct * 16 + (lane & 15);
    const int kbase = ks * 32 + (lane >> 4) * 8;
    unsigned short v[8];
#pragma unroll
    for (int j = 0; j < 8; ++j) {
        const int k = kbase + j;
        const float w = (k < 128) ? Wr[(size_t)k * 128 + col]
                                  : Ws[(size_t)(k - 128) * 128 + col];
        v[j] = f2bf(w);
    }
    *reinterpret_cast<uint4*>(Wp + (size_t)t * 8) = *reinterpret_cast<uint4*>(v);
}

__global__ void init_gcur(int* __restrict__ gcur, int NB) {
    const int t = blockIdx.x * blockDim.x + threadIdx.x;
    if (t < NB) gcur[t] = t * CAPB;
}

// ---------------------------------------------------------------------------
// Fused dispatch: PHASE A bucket split + x->bf16 conversion + W packs.
// stg rec (u64) = src(20) | dlocal(8)<<20 | w12(12)<<28.
// Stream-once stores (stg, XH) are nontemporal: keep L2/L3 lines for the
// gather's randomly re-read XH working set.
// ---------------------------------------------------------------------------
__global__ void __launch_bounds__(256)
prep_split(const int* __restrict__ src, const int* __restrict__ dst,
           const float* __restrict__ ew, int E, int N, int NB, int nchunkA,
           int* __restrict__ gcur, u64* __restrict__ stg,
           int* __restrict__ ovf_cnt, int4* __restrict__ ovf,
           const float* __restrict__ x, unsigned short* __restrict__ XH,
           int nconv,
           const float* __restrict__ Wr0, const float* __restrict__ Ws0,
           unsigned short* __restrict__ Wp0,
           const float* __restrict__ Wr1, const float* __restrict__ Ws1,
           unsigned short* __restrict__ Wp1) {
    const int b = blockIdx.x;
    if (b < nchunkA) {
        __shared__ int cnt[512];
        __shared__ int base[512];
        for (int t = threadIdx.x; t < NB; t += 256) cnt[t] = 0;
        __syncthreads();
        const int lo = b * CHUNK_A;
        const int hi = min(lo + CHUNK_A, E);
        int dreg[CHUNK_A / 256];
#pragma unroll
        for (int k = 0; k < CHUNK_A / 256; ++k) {
            const int i = lo + k * 256 + threadIdx.x;
            int d = -1;
            if (i < hi) d = dst[i];
            dreg[k] = d;
            if (d >= 0) atomicAdd(&cnt[d >> 8], 1);
        }
        __syncthreads();
        for (int t = threadIdx.x; t < NB; t += 256) {
            base[t] = atomicAdd(&gcur[t], cnt[t]);
            cnt[t] = 0;
        }
        __syncthreads();
#pragma unroll
        for (int k = 0; k < CHUNK_A / 256; ++k) {
            const int i = lo + k * 256 + threadIdx.x;
            const int d = dreg[k];
            if (d < 0) continue;
            const int bk = d >> 8;
            const int off = atomicAdd(&cnt[bk], 1);
            const int gi = base[bk] + off;
            if (gi < (bk + 1) * CAPB) {
                const unsigned w12 = min(4095u, (unsigned)__float2int_rn(ew[i] * 4095.f));
                const u64 rec = (u64)(unsigned)src[i] | ((u64)(unsigned)(d & 255) << 20)
                              | ((u64)w12 << 28);
                __builtin_nontemporal_store(rec, stg + gi);
            } else {
                const int o = atomicAdd(ovf_cnt, 1);
                if (o < OVF_CAP)
                    ovf[o] = make_int4(src[i], d, __float_as_int(ew[i]), 0);
            }
        }
    } else if (b < nchunkA + nconv) {
        const int i = (b - nchunkA) * 256 + threadIdx.x;
        if (i >= N * 32) return;
        float4 v = reinterpret_cast<const float4*>(x)[i];
        uint2v pk;
        pk.x = (unsigned)f2bf(v.x) | ((unsigned)f2bf(v.y) << 16);
        pk.y = (unsigned)f2bf(v.z) | ((unsigned)f2bf(v.w) << 16);
        __builtin_nontemporal_store(pk, reinterpret_cast<uint2v*>(XH) + i);
    } else if (b < nchunkA + nconv + 16) {
        pack_W_body(Wr0, Ws0, Wp0, (b - nchunkA - nconv) * 256 + threadIdx.x);
    } else {
        pack_W_body(Wr1, Ws1, Wp1, (b - nchunkA - nconv - 16) * 256 + threadIdx.x);
    }
}

// ---------------------------------------------------------------------------
// PHASE B: one block per bucket; writes confined to 48KB ELL region.
// ell rec (u32) = src(20) | w12(12)<<20. pos[d] = final degree.
// ---------------------------------------------------------------------------
__global__ void __launch_bounds__(256)
build_ell(const u64* __restrict__ stg, const int* __restrict__ gcur,
          int NB, int* __restrict__ pos, unsigned* __restrict__ ell,
          int* __restrict__ ovf_cnt, int4* __restrict__ ovf) {
    const int b = blockIdx.x;
    const int beg = b * CAPB;
    const int end = min(gcur[b], (b + 1) * CAPB);
    for (int i = beg + threadIdx.x; i < end; i += 256) {
        const u64 r = __builtin_nontemporal_load(stg + i);
        const int d = b * BWN + (int)((r >> 20) & 0xFF);
        const int slot = atomicAdd(&pos[d], 1);
        if (slot < SLOTS) {
            ell[(size_t)d * SLOTS + slot] =
                (unsigned)(r & 0xFFFFF) | ((unsigned)(r >> 28) << 20);
        } else {
            const int o = atomicAdd(ovf_cnt, 1);
            if (o < OVF_CAP) {
                const float w = (float)((r >> 28) & 0xFFF) * (1.f / 4095.f);
                ovf[o] = make_int4((int)(r & 0xFFFFF), d, __float_as_int(w), 0);
            }
        }
    }
}

// ---------------------------------------------------------------------------
// Overflow fixup: ONE wave, edges processed serially (program-order safe).
// ---------------------------------------------------------------------------
template <bool WEIGHTED>
__global__ void ovf_fixup(const unsigned short* __restrict__ XH,
                          const int* __restrict__ ovf_cnt,
                          const int4* __restrict__ ovf,
                          unsigned short* __restrict__ AGG) {
    const int n = min(*ovf_cnt, OVF_CAP);
    const int lane = threadIdx.x;   // 64 threads
    for (int e = 0; e < n; ++e) {
        const int4 r = ovf[e];
        const float w = WEIGHTED ? __int_as_float(r.z) : 1.f;
        const unsigned u = *reinterpret_cast<const unsigned*>(
            XH + (size_t)(unsigned)r.x * 128 + lane * 2);
        unsigned* pa = reinterpret_cast<unsigned*>(
            AGG + (size_t)r.y * 128 + lane * 2);
        const unsigned cur = *pa;
        const float ax = bf2f_lo(cur) + w * bf2f_lo(u);
        const float ay = bf2f_hi(cur) + w * bf2f_hi(u);
        *pa = (unsigned)f2bf(ax) | ((unsigned)f2bf(ay) << 16);
    }
}

// ---------------------------------------------------------------------------
// Gather-aggregate (node-major ELL, 4B records, dense buffers): one wave per
// node; lane group g=lane>>4 handles slot i+g (16 lanes x 16B = 256B row).
// ell record loads + AGG row stores nontemporal (stream-once; keep L2/L3
// for the randomly re-read XH rows).
// ---------------------------------------------------------------------------
template <bool WEIGHTED>
__global__ void __launch_bounds__(256)
gather_ell(const unsigned short* __restrict__ XH,
           const int* __restrict__ pos,
           const unsigned* __restrict__ ell,
           unsigned short* __restrict__ AGG,
           int N) {
    const int node = blockIdx.x * 4 + (threadIdx.x >> 6);
    const int lane = threadIdx.x & 63;
    if (node >= N) return;
    const int g = lane >> 4;      // slot subgroup 0..3
    const int c = lane & 15;      // 16B column -> feats c*8..c*8+7

    const int deg = min(pos[node], SLOTS);
    const unsigned* ebase = ell + (size_t)node * SLOTS;

    float acc[8];
#pragma unroll
    for (int j = 0; j < 8; ++j) acc[j] = 0.f;

    auto body = [&](int i) {
        const unsigned r = __builtin_nontemporal_load(ebase + i);
        const float w = WEIGHTED ? (float)(r >> 20) * (1.f / 4095.f) : 1.f;
        const uint4 v = *reinterpret_cast<const uint4*>(
            XH + (size_t)(r & 0xFFFFF) * 128 + c * 8);
        acc[0] += w * bf2f_lo(v.x); acc[1] += w * bf2f_hi(v.x);
        acc[2] += w * bf2f_lo(v.y); acc[3] += w * bf2f_hi(v.y);
        acc[4] += w * bf2f_lo(v.z); acc[5] += w * bf2f_hi(v.z);
        acc[6] += w * bf2f_lo(v.w); acc[7] += w * bf2f_hi(v.w);
    };

    int i = g;
    for (; i + 12 < deg; i += 16) { body(i); body(i + 4); body(i + 8); body(i + 12); }
    for (; i < deg; i += 4) body(i);

#pragma unroll
    for (int j = 0; j < 8; ++j) {
        acc[j] += __shfl_xor(acc[j], 16);
        acc[j] += __shfl_xor(acc[j], 32);
    }

    if (lane < 16) {
        uint4v o;
        o.x = (unsigned)f2bf(acc[0]) | ((unsigned)f2bf(acc[1]) << 16);
        o.y = (unsigned)f2bf(acc[2]) | ((unsigned)f2bf(acc[3]) << 16);
        o.z = (unsigned)f2bf(acc[4]) | ((unsigned)f2bf(acc[5]) << 16);
        o.w = (unsigned)f2bf(acc[6]) | ((unsigned)f2bf(acc[7]) << 16);
        __builtin_nontemporal_store(o, reinterpret_cast<uint4v*>(
            AGG + (size_t)node * 128 + c * 8));
    }
}

// ---------------------------------------------------------------------------
// MFMA GEMM: out = relu([AGG | XH] @ [Wr;Ws] + br), K=256, bf16 in, fp32 acc.
// Wave = 32 rows x 128 cols (2x8 fragments of 16x16x32). A direct from global.
// Epilogue stores nontemporal (stream-once).
// ---------------------------------------------------------------------------
template <bool TO_BF16>
__global__ void __launch_bounds__(256)
gemm_mfma(const unsigned short* __restrict__ AGG,
          const unsigned short* __restrict__ XH,
          const unsigned short* __restrict__ Wp,
          const float* __restrict__ br,
          float* __restrict__ out,
          unsigned short* __restrict__ XHo,
          int N) {
    const int tid = threadIdx.x;
    const int wave = tid >> 6;
    const int lane = tid & 63;
    const int r0 = blockIdx.x * 128 + wave * 32;
    const int lk = (lane >> 4) * 8;

    int ra = r0 + (lane & 15);
    int rb = ra + 16;
    if (ra >= N) ra = N - 1;   // clamped loads; stores guarded below
    if (rb >= N) rb = N - 1;
    const unsigned short* paga = AGG + (size_t)ra * 128 + lk;
    const unsigned short* pagb = AGG + (size_t)rb * 128 + lk;
    const unsigned short* pxha = XH + (size_t)ra * 128 + lk;
    const unsigned short* pxhb = XH + (size_t)rb * 128 + lk;
    const unsigned short* pw = Wp + (size_t)lane * 8;

    f32x4 acc[2][8];
#pragma unroll
    for (int rt = 0; rt < 2; ++rt)
#pragma unroll
        for (int ct = 0; ct < 8; ++ct)
            acc[rt][ct] = (f32x4){0.f, 0.f, 0.f, 0.f};

#pragma unroll
    for (int ks = 0; ks < 8; ++ks) {
        const bf16x8 a0 = (ks < 4)
            ? *reinterpret_cast<const bf16x8*>(paga + ks * 32)
            : *reinterpret_cast<const bf16x8*>(pxha + (ks - 4) * 32);
        const bf16x8 a1 = (ks < 4)
            ? *reinterpret_cast<const bf16x8*>(pagb + ks * 32)
            : *reinterpret_cast<const bf16x8*>(pxhb + (ks - 4) * 32);
#pragma unroll
        for (int ct = 0; ct < 8; ++ct) {
            const bf16x8 b = *reinterpret_cast<const bf16x8*>(pw + (((ks << 3) + ct) << 9));
            acc[0][ct] = __builtin_amdgcn_mfma_f32_16x16x32_bf16(a0, b, acc[0][ct], 0, 0, 0);
            acc[1][ct] = __builtin_amdgcn_mfma_f32_16x16x32_bf16(a1, b, acc[1][ct], 0, 0, 0);
        }
    }

    const int crow = (lane >> 4) * 4;
    const int ccol = lane & 15;
#pragma unroll
    for (int ct = 0; ct < 8; ++ct) {
        const int col = ct * 16 + ccol;
        const float bias = br[col];
#pragma unroll
        for (int rt = 0; rt < 2; ++rt) {
#pragma unroll
            for (int reg = 0; reg < 4; ++reg) {
                const int row = r0 + rt * 16 + crow + reg;
                if (row >= N) continue;
                const float v = fmaxf(acc[rt][ct][reg] + bias, 0.f);
                if (TO_BF16) {
                    __builtin_nontemporal_store(f2bf(v), XHo + (size_t)row * 128 + col);
                } else {
                    __builtin_nontemporal_store(v, out + (size_t)row * 128 + col);
                }
            }
        }
    }
}

extern "C" void kernel_launch(void* const* d_in, const int* in_sizes, int n_in,
                              void* d_out, int out_size, void* d_ws, size_t ws_size,
                              hipStream_t stream) {
    const float* x  = (const float*)d_in[0];
    const int*   ei = (const int*)d_in[1];     // [2, E] int32 (JAX x64 disabled)
    const float* ew = (const float*)d_in[2];
    const float* Wr0 = (const float*)d_in[3];
    const float* br0 = (const float*)d_in[4];
    const float* Ws0 = (const float*)d_in[5];
    const float* Wr1 = (const float*)d_in[6];
    const float* br1 = (const float*)d_in[7];
    const float* Ws1 = (const float*)d_in[8];

    const int N = in_sizes[0] / D_FEAT;
    const int E = in_sizes[1] / 2;
    const int* src = ei;
    const int* dst = ei + E;
    const int NB = (N + BWN - 1) / BWN;      // 391 for N=100k (<=512)

    // ---- workspace carve-up (16B aligned), ~71 MB ----
    char* w = (char*)d_ws;
    auto carve = [&](size_t bytes) { char* p = w; w += (bytes + 15) & ~(size_t)15; return p; };
    unsigned short* XH  = (unsigned short*)carve((size_t)N * 128 * 2);    // 25.6 MB
    unsigned short* AGG = (unsigned short*)carve((size_t)N * 128 * 2);    // 25.6 MB
    unsigned short* Wp0 = (unsigned short*)carve(256 * 128 * 2);
    unsigned short* Wp1 = (unsigned short*)carve(256 * 128 * 2);
    int*      pos     = (int*)     carve((size_t)N * 4);                  // 0.4 MB
    int*      ovf_cnt = (int*)     carve(16);
    int*      gcur    = (int*)     carve(512 * 4);
    int4*     ovf     = (int4*)    carve((size_t)OVF_CAP * 16);           // 128 KB
    unsigned* ell     = (unsigned*)carve((size_t)N * SLOTS * 4);          // 19.2 MB

    float* out = (float*)d_out;
    // stg staging lives in d_out (51.2 MB) — dead before the L1 GEMM writes out.
    u64* stg = (u64*)d_out;                                               // 14.4 MB used

    const int nconv = (N * 32 + 255) / 256;
    const int nchunkA = (E + CHUNK_A - 1) / CHUNK_A;
    const int gather_blocks = (N + 3) / 4;
    const int gemm_blocks = (N + 127) / 128;

    // ---- init ----
    hipMemsetAsync(pos, 0, (size_t)N * 4, stream);
    hipMemsetAsync(ovf_cnt, 0, 4, stream);
    init_gcur<<<2, 256, 0, stream>>>(gcur, NB);

    // ---- Phase A split + prep (one dispatch) ----
    prep_split<<<nchunkA + nconv + 32, 256, 0, stream>>>(
        src, dst, ew, E, N, NB, nchunkA, gcur, stg, ovf_cnt, ovf,
        x, XH, nconv, Wr0, Ws0, Wp0, Wr1, Ws1, Wp1);

    // ---- Phase B: per-bucket ELL build ----
    build_ell<<<NB, 256, 0, stream>>>(stg, gcur, NB, pos, ell, ovf_cnt, ovf);

    // ---- Layer 0 (weighted) ----
    gather_ell<true><<<gather_blocks, 256, 0, stream>>>(XH, pos, ell, AGG, N);
    ovf_fixup<true><<<1, 64, 0, stream>>>(XH, ovf_cnt, ovf, AGG);
    gemm_mfma<true><<<gemm_blocks, 256, 0, stream>>>(AGG, XH, Wp0, br0, nullptr, XH, N);

    // ---- Layer 1 (unweighted — reference omits edge_weight here) ----
    gather_ell<false><<<gather_blocks, 256, 0, stream>>>(XH, pos, ell, AGG, N);
    ovf_fixup<false><<<1, 64, 0, stream>>>(XH, ovf_cnt, ovf, AGG);
    gemm_mfma<false><<<gemm_blocks, 256, 0, stream>>>(AGG, XH, Wp1, br1, out, nullptr, N);
}

// Round 23
// 279.966 us; speedup vs baseline: 1.1619x; 1.1619x over previous
//
#include <hip/hip_runtime.h>
#include <hip/hip_bf16.h>

#ifndef D_FEAT
#define D_FEAT 128
#endif

#define SLOTS 48          // ELL width: 192B row = 3 aligned 64B lines
#define OVF_CAP 8192
#define BWN 256           // bucket width (nodes); NB = ceil(N/256)
#define CAPB 4608         // staging capacity/bucket (mean 4096 + 8 sigma)
#define CHUNK_A 4096      // edges per split block

typedef __attribute__((ext_vector_type(8))) short bf16x8;
typedef __attribute__((ext_vector_type(4))) float f32x4;
typedef unsigned long long u64;

// ---------------- bf16 helpers (RN-even) ----------------
__device__ __forceinline__ unsigned short f2bf(float f) {
    union { float f; unsigned u; } v; v.f = f;
    unsigned r = v.u + 0x7FFF + ((v.u >> 16) & 1);
    return (unsigned short)(r >> 16);
}
__device__ __forceinline__ float bf2f_lo(unsigned u) {
    union { unsigned u; float f; } v; v.u = u << 16; return v.f;
}
__device__ __forceinline__ float bf2f_hi(unsigned u) {
    union { unsigned u; float f; } v; v.u = u & 0xFFFF0000u; return v.f;
}

// ---------------------------------------------------------------------------
// W-pack body (canonical B-fragment order):
// Wp[((ks*8+ct)*64+lane)*8+j] = W[ks*32+(lane>>4)*8+j][ct*16+(lane&15)]
// ---------------------------------------------------------------------------
__device__ __forceinline__ void pack_W_body(const float* __restrict__ Wr,
                                            const float* __restrict__ Ws,
                                            unsigned short* __restrict__ Wp,
                                            int t) {
    const int lane = t & 63;
    const int ct = (t >> 6) & 7;
    const int ks = t >> 9;
    const int col = ct * 16 + (lane & 15);
    const int kbase = ks * 32 + (lane >> 4) * 8;
    unsigned short v[8];
#pragma unroll
    for (int j = 0; j < 8; ++j) {
        const int k = kbase + j;
        const float w = (k < 128) ? Wr[(size_t)k * 128 + col]
                                  : Ws[(size_t)(k - 128) * 128 + col];
        v[j] = f2bf(w);
    }
    *reinterpret_cast<uint4*>(Wp + (size_t)t * 8) = *reinterpret_cast<uint4*>(v);
}

__global__ void init_gcur(int* __restrict__ gcur, int NB) {
    const int t = blockIdx.x * blockDim.x + threadIdx.x;
    if (t < NB) gcur[t] = t * CAPB;
}

// ---------------------------------------------------------------------------
// Fused dispatch:
// blocks [0, nchunkA): PHASE A bucket split — per-block LDS counts over NB
//   buckets, block-level global reservation, contiguous per-(block,bucket)
//   record runs (~84B) -> near-full-line writes (L2 write-merging; R22
//   proved nontemporal hints here cost +45us by defeating the merge).
//   stg rec (u64) = src(20) | dlocal(8)<<20 | w12(12)<<28.
// blocks [nchunkA, +nconv): x fp32 -> bf16 dense XH[N][128].
// next 16: pack W0; next 16: pack W1.
// ---------------------------------------------------------------------------
__global__ void __launch_bounds__(256)
prep_split(const int* __restrict__ src, const int* __restrict__ dst,
           const float* __restrict__ ew, int E, int N, int NB, int nchunkA,
           int* __restrict__ gcur, u64* __restrict__ stg,
           int* __restrict__ ovf_cnt, int4* __restrict__ ovf,
           const float* __restrict__ x, unsigned short* __restrict__ XH,
           int nconv,
           const float* __restrict__ Wr0, const float* __restrict__ Ws0,
           unsigned short* __restrict__ Wp0,
           const float* __restrict__ Wr1, const float* __restrict__ Ws1,
           unsigned short* __restrict__ Wp1) {
    const int b = blockIdx.x;
    if (b < nchunkA) {
        __shared__ int cnt[512];
        __shared__ int base[512];
        for (int t = threadIdx.x; t < NB; t += 256) cnt[t] = 0;
        __syncthreads();
        const int lo = b * CHUNK_A;
        const int hi = min(lo + CHUNK_A, E);
        int dreg[CHUNK_A / 256];
#pragma unroll
        for (int k = 0; k < CHUNK_A / 256; ++k) {
            const int i = lo + k * 256 + threadIdx.x;
            int d = -1;
            if (i < hi) d = dst[i];
            dreg[k] = d;
            if (d >= 0) atomicAdd(&cnt[d >> 8], 1);
        }
        __syncthreads();
        for (int t = threadIdx.x; t < NB; t += 256) {
            base[t] = atomicAdd(&gcur[t], cnt[t]);
            cnt[t] = 0;
        }
        __syncthreads();
#pragma unroll
        for (int k = 0; k < CHUNK_A / 256; ++k) {
            const int i = lo + k * 256 + threadIdx.x;
            const int d = dreg[k];
            if (d < 0) continue;
            const int bk = d >> 8;
            const int off = atomicAdd(&cnt[bk], 1);
            const int gi = base[bk] + off;
            if (gi < (bk + 1) * CAPB) {
                const unsigned w12 = min(4095u, (unsigned)__float2int_rn(ew[i] * 4095.f));
                stg[gi] = (u64)(unsigned)src[i] | ((u64)(unsigned)(d & 255) << 20)
                        | ((u64)w12 << 28);
            } else {
                const int o = atomicAdd(ovf_cnt, 1);
                if (o < OVF_CAP)
                    ovf[o] = make_int4(src[i], d, __float_as_int(ew[i]), 0);
            }
        }
    } else if (b < nchunkA + nconv) {
        const int i = (b - nchunkA) * 256 + threadIdx.x;
        if (i >= N * 32) return;
        float4 v = reinterpret_cast<const float4*>(x)[i];
        unsigned lo = (unsigned)f2bf(v.x) | ((unsigned)f2bf(v.y) << 16);
        unsigned hi = (unsigned)f2bf(v.z) | ((unsigned)f2bf(v.w) << 16);
        reinterpret_cast<uint2*>(XH)[i] = make_uint2(lo, hi);
    } else if (b < nchunkA + nconv + 16) {
        pack_W_body(Wr0, Ws0, Wp0, (b - nchunkA - nconv) * 256 + threadIdx.x);
    } else {
        pack_W_body(Wr1, Ws1, Wp1, (b - nchunkA - nconv - 16) * 256 + threadIdx.x);
    }
}

// ---------------------------------------------------------------------------
// PHASE B: one block per bucket. Sequential bucket read; random writes
// confined to the bucket's 48KB ELL region (L2-resident, lines merge).
// ell rec (u32) = src(20) | w12(12)<<20. pos[d] = final degree.
// ---------------------------------------------------------------------------
__global__ void __launch_bounds__(256)
build_ell(const u64* __restrict__ stg, const int* __restrict__ gcur,
          int NB, int* __restrict__ pos, unsigned* __restrict__ ell,
          int* __restrict__ ovf_cnt, int4* __restrict__ ovf) {
    const int b = blockIdx.x;
    const int beg = b * CAPB;
    const int end = min(gcur[b], (b + 1) * CAPB);
    for (int i = beg + threadIdx.x; i < end; i += 256) {
        const u64 r = stg[i];
        const int d = b * BWN + (int)((r >> 20) & 0xFF);
        const int slot = atomicAdd(&pos[d], 1);
        if (slot < SLOTS) {
            ell[(size_t)d * SLOTS + slot] =
                (unsigned)(r & 0xFFFFF) | ((unsigned)(r >> 28) << 20);
        } else {
            const int o = atomicAdd(ovf_cnt, 1);
            if (o < OVF_CAP) {
                const float w = (float)((r >> 28) & 0xFFF) * (1.f / 4095.f);
                ovf[o] = make_int4((int)(r & 0xFFFFF), d, __float_as_int(w), 0);
            }
        }
    }
}

// ---------------------------------------------------------------------------
// Overflow fixup: ONE wave, edges processed serially (program-order safe).
// ---------------------------------------------------------------------------
template <bool WEIGHTED>
__global__ void ovf_fixup(const unsigned short* __restrict__ XH,
                          const int* __restrict__ ovf_cnt,
                          const int4* __restrict__ ovf,
                          unsigned short* __restrict__ AGG) {
    const int n = min(*ovf_cnt, OVF_CAP);
    const int lane = threadIdx.x;   // 64 threads
    for (int e = 0; e < n; ++e) {
        const int4 r = ovf[e];
        const float w = WEIGHTED ? __int_as_float(r.z) : 1.f;
        const unsigned u = *reinterpret_cast<const unsigned*>(
            XH + (size_t)(unsigned)r.x * 128 + lane * 2);
        unsigned* pa = reinterpret_cast<unsigned*>(
            AGG + (size_t)r.y * 128 + lane * 2);
        const unsigned cur = *pa;
        const float ax = bf2f_lo(cur) + w * bf2f_lo(u);
        const float ay = bf2f_hi(cur) + w * bf2f_hi(u);
        *pa = (unsigned)f2bf(ax) | ((unsigned)f2bf(ay) << 16);
    }
}

// ---------------------------------------------------------------------------
// Gather-aggregate (node-major ELL, 4B records, dense buffers): one wave per
// node; lane group g=lane>>4 handles slot i+g (16 lanes x 16B = 256B row).
// Cross-lane reduce (xor 16,32); lanes 0-15 write the agg row.
// ---------------------------------------------------------------------------
template <bool WEIGHTED>
__global__ void __launch_bounds__(256)
gather_ell(const unsigned short* __restrict__ XH,
           const int* __restrict__ pos,
           const unsigned* __restrict__ ell,
           unsigned short* __restrict__ AGG,
           int N) {
    const int node = blockIdx.x * 4 + (threadIdx.x >> 6);
    const int lane = threadIdx.x & 63;
    if (node >= N) return;
    const int g = lane >> 4;      // slot subgroup 0..3
    const int c = lane & 15;      // 16B column -> feats c*8..c*8+7

    const int deg = min(pos[node], SLOTS);
    const unsigned* ebase = ell + (size_t)node * SLOTS;

    float acc[8];
#pragma unroll
    for (int j = 0; j < 8; ++j) acc[j] = 0.f;

    auto body = [&](int i) {
        const unsigned r = ebase[i];
        const float w = WEIGHTED ? (float)(r >> 20) * (1.f / 4095.f) : 1.f;
        const uint4 v = *reinterpret_cast<const uint4*>(
            XH + (size_t)(r & 0xFFFFF) * 128 + c * 8);
        acc[0] += w * bf2f_lo(v.x); acc[1] += w * bf2f_hi(v.x);
        acc[2] += w * bf2f_lo(v.y); acc[3] += w * bf2f_hi(v.y);
        acc[4] += w * bf2f_lo(v.z); acc[5] += w * bf2f_hi(v.z);
        acc[6] += w * bf2f_lo(v.w); acc[7] += w * bf2f_hi(v.w);
    };

    int i = g;
    for (; i + 12 < deg; i += 16) { body(i); body(i + 4); body(i + 8); body(i + 12); }
    for (; i < deg; i += 4) body(i);

#pragma unroll
    for (int j = 0; j < 8; ++j) {
        acc[j] += __shfl_xor(acc[j], 16);
        acc[j] += __shfl_xor(acc[j], 32);
    }

    if (lane < 16) {
        uint4 o;
        o.x = (unsigned)f2bf(acc[0]) | ((unsigned)f2bf(acc[1]) << 16);
        o.y = (unsigned)f2bf(acc[2]) | ((unsigned)f2bf(acc[3]) << 16);
        o.z = (unsigned)f2bf(acc[4]) | ((unsigned)f2bf(acc[5]) << 16);
        o.w = (unsigned)f2bf(acc[6]) | ((unsigned)f2bf(acc[7]) << 16);
        *reinterpret_cast<uint4*>(AGG + (size_t)node * 128 + c * 8) = o;
    }
}

// ---------------------------------------------------------------------------
// MFMA GEMM: out = relu([AGG | XH] @ [Wr;Ws] + br), K=256, bf16 in, fp32 acc.
// Wave = 32 rows x 128 cols (2x8 fragments of 16x16x32). A direct from global.
// ---------------------------------------------------------------------------
template <bool TO_BF16>
__global__ void __launch_bounds__(256)
gemm_mfma(const unsigned short* __restrict__ AGG,
          const unsigned short* __restrict__ XH,
          const unsigned short* __restrict__ Wp,
          const float* __restrict__ br,
          float* __restrict__ out,
          unsigned short* __restrict__ XHo,
          int N) {
    const int tid = threadIdx.x;
    const int wave = tid >> 6;
    const int lane = tid & 63;
    const int r0 = blockIdx.x * 128 + wave * 32;
    const int lk = (lane >> 4) * 8;

    int ra = r0 + (lane & 15);
    int rb = ra + 16;
    if (ra >= N) ra = N - 1;   // clamped loads; stores guarded below
    if (rb >= N) rb = N - 1;
    const unsigned short* paga = AGG + (size_t)ra * 128 + lk;
    const unsigned short* pagb = AGG + (size_t)rb * 128 + lk;
    const unsigned short* pxha = XH + (size_t)ra * 128 + lk;
    const unsigned short* pxhb = XH + (size_t)rb * 128 + lk;
    const unsigned short* pw = Wp + (size_t)lane * 8;

    f32x4 acc[2][8];
#pragma unroll
    for (int rt = 0; rt < 2; ++rt)
#pragma unroll
        for (int ct = 0; ct < 8; ++ct)
            acc[rt][ct] = (f32x4){0.f, 0.f, 0.f, 0.f};

#pragma unroll
    for (int ks = 0; ks < 8; ++ks) {
        const bf16x8 a0 = (ks < 4)
            ? *reinterpret_cast<const bf16x8*>(paga + ks * 32)
            : *reinterpret_cast<const bf16x8*>(pxha + (ks - 4) * 32);
        const bf16x8 a1 = (ks < 4)
            ? *reinterpret_cast<const bf16x8*>(pagb + ks * 32)
            : *reinterpret_cast<const bf16x8*>(pxhb + (ks - 4) * 32);
#pragma unroll
        for (int ct = 0; ct < 8; ++ct) {
            const bf16x8 b = *reinterpret_cast<const bf16x8*>(pw + (((ks << 3) + ct) << 9));
            acc[0][ct] = __builtin_amdgcn_mfma_f32_16x16x32_bf16(a0, b, acc[0][ct], 0, 0, 0);
            acc[1][ct] = __builtin_amdgcn_mfma_f32_16x16x32_bf16(a1, b, acc[1][ct], 0, 0, 0);
        }
    }

    const int crow = (lane >> 4) * 4;
    const int ccol = lane & 15;
#pragma unroll
    for (int ct = 0; ct < 8; ++ct) {
        const int col = ct * 16 + ccol;
        const float bias = br[col];
#pragma unroll
        for (int rt = 0; rt < 2; ++rt) {
#pragma unroll
            for (int reg = 0; reg < 4; ++reg) {
                const int row = r0 + rt * 16 + crow + reg;
                if (row >= N) continue;
                const float v = fmaxf(acc[rt][ct][reg] + bias, 0.f);
                if (TO_BF16) {
                    XHo[(size_t)row * 128 + col] = f2bf(v);
                } else {
                    out[(size_t)row * 128 + col] = v;
                }
            }
        }
    }
}

extern "C" void kernel_launch(void* const* d_in, const int* in_sizes, int n_in,
                              void* d_out, int out_size, void* d_ws, size_t ws_size,
                              hipStream_t stream) {
    const float* x  = (const float*)d_in[0];
    const int*   ei = (const int*)d_in[1];     // [2, E] int32 (JAX x64 disabled)
    const float* ew = (const float*)d_in[2];
    const float* Wr0 = (const float*)d_in[3];
    const float* br0 = (const float*)d_in[4];
    const float* Ws0 = (const float*)d_in[5];
    const float* Wr1 = (const float*)d_in[6];
    const float* br1 = (const float*)d_in[7];
    const float* Ws1 = (const float*)d_in[8];

    const int N = in_sizes[0] / D_FEAT;
    const int E = in_sizes[1] / 2;
    const int* src = ei;
    const int* dst = ei + E;
    const int NB = (N + BWN - 1) / BWN;      // 391 for N=100k (<=512)

    // ---- workspace carve-up (16B aligned), ~71 MB ----
    char* w = (char*)d_ws;
    auto carve = [&](size_t bytes) { char* p = w; w += (bytes + 15) & ~(size_t)15; return p; };
    unsigned short* XH  = (unsigned short*)carve((size_t)N * 128 * 2);    // 25.6 MB
    unsigned short* AGG = (unsigned short*)carve((size_t)N * 128 * 2);    // 25.6 MB
    unsigned short* Wp0 = (unsigned short*)carve(256 * 128 * 2);
    unsigned short* Wp1 = (unsigned short*)carve(256 * 128 * 2);
    int*      pos     = (int*)     carve((size_t)N * 4);                  // 0.4 MB
    int*      ovf_cnt = (int*)     carve(16);
    int*      gcur    = (int*)     carve(512 * 4);
    int4*     ovf     = (int4*)    carve((size_t)OVF_CAP * 16);           // 128 KB
    unsigned* ell     = (unsigned*)carve((size_t)N * SLOTS * 4);          // 19.2 MB

    float* out = (float*)d_out;
    // stg staging lives in d_out (51.2 MB) — dead before the L1 GEMM writes out.
    u64* stg = (u64*)d_out;                                               // 14.4 MB used

    const int nconv = (N * 32 + 255) / 256;
    const int nchunkA = (E + CHUNK_A - 1) / CHUNK_A;
    const int gather_blocks = (N + 3) / 4;
    const int gemm_blocks = (N + 127) / 128;

    // ---- init ----
    hipMemsetAsync(pos, 0, (size_t)N * 4, stream);
    hipMemsetAsync(ovf_cnt, 0, 4, stream);
    init_gcur<<<2, 256, 0, stream>>>(gcur, NB);

    // ---- Phase A split + prep (one dispatch) ----
    prep_split<<<nchunkA + nconv + 32, 256, 0, stream>>>(
        src, dst, ew, E, N, NB, nchunkA, gcur, stg, ovf_cnt, ovf,
        x, XH, nconv, Wr0, Ws0, Wp0, Wr1, Ws1, Wp1);

    // ---- Phase B: per-bucket ELL build ----
    build_ell<<<NB, 256, 0, stream>>>(stg, gcur, NB, pos, ell, ovf_cnt, ovf);

    // ---- Layer 0 (weighted) ----
    gather_ell<true><<<gather_blocks, 256, 0, stream>>>(XH, pos, ell, AGG, N);
    ovf_fixup<true><<<1, 64, 0, stream>>>(XH, ovf_cnt, ovf, AGG);
    gemm_mfma<true><<<gemm_blocks, 256, 0, stream>>>(AGG, XH, Wp0, br0, nullptr, XH, N);

    // ---- Layer 1 (unweighted — reference omits edge_weight here) ----
    gather_ell<false><<<gather_blocks, 256, 0, stream>>>(XH, pos, ell, AGG, N);
    ovf_fixup<false><<<1, 64, 0, stream>>>(XH, ovf_cnt, ovf, AGG);
    gemm_mfma<false><<<gemm_blocks, 256, 0, stream>>>(AGG, XH, Wp1, br1, out, nullptr, N);
}